// Round 2
// baseline (1098.568 us; speedup 1.0000x reference)
//
#include <hip/hip_runtime.h>
#include <hip/hip_bf16.h>
#include <cstdint>

// Problem constants (hard-coded from reference: B=4, C=512, H=W=256, DS=8)
#define B_    4
#define C_    512
#define H_    256
#define W_    256
#define HP_   32          // H/DS
#define WP_   32          // W/DS
#define N_    1024        // HP*WP
#define KD_   64          // C/8
#define MR_   640         // 64 (q) + 64 (k) + 512 (v) stacked rows

// ---------------------------------------------------------------------------
// Concat Wq/Wk/Wv -> Wcat [640 x 512], bq/bk/bv -> bcat [640]
// ---------------------------------------------------------------------------
__global__ __launch_bounds__(256) void concat_kernel(
    const float* __restrict__ Wq, const float* __restrict__ bq,
    const float* __restrict__ Wk, const float* __restrict__ bk,
    const float* __restrict__ Wv, const float* __restrict__ bv,
    float* __restrict__ Wcat, float* __restrict__ bcat)
{
    int tid = blockIdx.x * 256 + threadIdx.x;
    if (tid < 64 * C_)            Wcat[tid] = Wq[tid];
    else if (tid < 128 * C_)      Wcat[tid] = Wk[tid - 64 * C_];
    else if (tid < MR_ * C_)      Wcat[tid] = Wv[tid - 128 * C_];
    if (tid < MR_)
        bcat[tid] = (tid < 64) ? bq[tid] : (tid < 128) ? bk[tid - 64] : bv[tid - 128];
}

// ---------------------------------------------------------------------------
// 8x8 average pool: x [B,C,256,256] -> xf [B*C, 1024]   (n = ph*32+pw)
// ---------------------------------------------------------------------------
__global__ __launch_bounds__(256) void pool_kernel(
    const float* __restrict__ x, float* __restrict__ xf)
{
    int idx = blockIdx.x * 256 + threadIdx.x;      // 0 .. 2*1024*1024-1
    int pw  = idx & 31;
    int ph  = (idx >> 5) & 31;
    int bc  = idx >> 10;                           // b*512 + c
    const float* src = x + ((size_t)bc * H_ + ph * 8) * W_ + pw * 8;
    float s = 0.f;
#pragma unroll
    for (int r = 0; r < 8; ++r) {
        float4 a = *(const float4*)(src + (size_t)r * W_);
        float4 b = *(const float4*)(src + (size_t)r * W_ + 4);
        s += (a.x + a.y + a.z + a.w) + (b.x + b.y + b.z + b.w);
    }
    xf[(size_t)bc * N_ + ph * WP_ + pw] = s * (1.f / 64.f);
}

// ---------------------------------------------------------------------------
// Generic batched tiled fp32 GEMM: C[m,n] = alpha * sum_k A(m,k)*B(k,n) + bias[m]
//   A(m,k) = A[m*sam + k*sak], B(k,n) = B[k*sbk + n*sbn]
//   AK  -> A is k-fast (sak==1), else m-fast (sam==1)
//   BNF -> B is n-fast (sbn==1), else k-fast (sbk==1)
// Tile: BM=64, BN=128, BK=16; 256 threads; 4x8 per thread.
// All dims divide tiles exactly -> no bounds checks.
// ---------------------------------------------------------------------------
template <bool AK, bool BNF>
__global__ __launch_bounds__(256) void gemm_kernel(
    const float* __restrict__ A, long sam, long sak, long sAb,
    const float* __restrict__ Bm, long sbk, long sbn, long sBb,
    float* __restrict__ C, long ldc, long sCb,
    int Kdim, const float* __restrict__ bias, float alpha)
{
    constexpr int BM = 64, BN = 128, BK = 16;
    __shared__ float As[BK][BM];
    __shared__ float Bs[BK][BN];

    const int t  = threadIdx.x;
    const int tx = t & 15;        // n-dir
    const int ty = t >> 4;        // m-dir
    const int m0 = blockIdx.y * BM;
    const int n0 = blockIdx.x * BN;

    A  += (size_t)blockIdx.z * sAb;
    Bm += (size_t)blockIdx.z * sBb;
    C  += (size_t)blockIdx.z * sCb;

    float acc[4][8];
#pragma unroll
    for (int i = 0; i < 4; ++i)
#pragma unroll
        for (int j = 0; j < 8; ++j) acc[i][j] = 0.f;

    for (int kt = 0; kt < Kdim; kt += BK) {
        // ---- stage A tile (64 x 16) ----
        if constexpr (AK) {
            const int m  = t >> 2;
            const int kk = (t & 3) << 2;
            const float4 a4 = *(const float4*)(A + (size_t)(m0 + m) * sam + (kt + kk));
            As[kk + 0][m] = a4.x; As[kk + 1][m] = a4.y;
            As[kk + 2][m] = a4.z; As[kk + 3][m] = a4.w;
        } else {
            const int kk = t >> 4;
            const int m  = (t & 15) << 2;
            const float4 a4 = *(const float4*)(A + (size_t)(kt + kk) * sak + (m0 + m));
            *(float4*)&As[kk][m] = a4;
        }
        // ---- stage B tile (16 x 128) ----
        if constexpr (BNF) {
            const int kk = t >> 4;
            const int n  = (t & 15) << 3;
            const float* pb = Bm + (size_t)(kt + kk) * sbk + (n0 + n);
            *(float4*)&Bs[kk][n]     = *(const float4*)pb;
            *(float4*)&Bs[kk][n + 4] = *(const float4*)(pb + 4);
        } else {
            const int n  = t >> 1;
            const int kk = (t & 1) << 3;
            const float* pb = Bm + (size_t)(n0 + n) * sbn + (kt + kk);
            float4 b0 = *(const float4*)pb;
            float4 b1 = *(const float4*)(pb + 4);
            Bs[kk + 0][n] = b0.x; Bs[kk + 1][n] = b0.y;
            Bs[kk + 2][n] = b0.z; Bs[kk + 3][n] = b0.w;
            Bs[kk + 4][n] = b1.x; Bs[kk + 5][n] = b1.y;
            Bs[kk + 6][n] = b1.z; Bs[kk + 7][n] = b1.w;
        }
        __syncthreads();

#pragma unroll
        for (int k = 0; k < BK; ++k) {
            const float4 av = *(const float4*)&As[k][ty * 4];
            const float4 b0 = *(const float4*)&Bs[k][tx * 4];
            const float4 b1 = *(const float4*)&Bs[k][64 + tx * 4];
            const float a[4]  = {av.x, av.y, av.z, av.w};
            const float bb[8] = {b0.x, b0.y, b0.z, b0.w, b1.x, b1.y, b1.z, b1.w};
#pragma unroll
            for (int i = 0; i < 4; ++i)
#pragma unroll
                for (int j = 0; j < 8; ++j)
                    acc[i][j] = fmaf(a[i], bb[j], acc[i][j]);
        }
        __syncthreads();
    }

#pragma unroll
    for (int i = 0; i < 4; ++i) {
        const int m = m0 + ty * 4 + i;
        const float bi = bias ? bias[m] : 0.f;
        float4 o0, o1;
        o0.x = alpha * acc[i][0] + bi; o0.y = alpha * acc[i][1] + bi;
        o0.z = alpha * acc[i][2] + bi; o0.w = alpha * acc[i][3] + bi;
        o1.x = alpha * acc[i][4] + bi; o1.y = alpha * acc[i][5] + bi;
        o1.z = alpha * acc[i][6] + bi; o1.w = alpha * acc[i][7] + bi;
        *(float4*)(C + (size_t)m * ldc + n0 + tx * 4)      = o0;
        *(float4*)(C + (size_t)m * ldc + n0 + 64 + tx * 4) = o1;
    }
}

// ---------------------------------------------------------------------------
// Row softmax over attn [rows, 1024], in place. One 256-thread block per row.
// ---------------------------------------------------------------------------
__global__ __launch_bounds__(256) void softmax_kernel(float* __restrict__ attn)
{
    __shared__ float sm[4], ss[4];
    float* p = attn + (size_t)blockIdx.x * N_;
    const int t = threadIdx.x;
    float4 v = *(const float4*)&p[t * 4];

    float m = fmaxf(fmaxf(v.x, v.y), fmaxf(v.z, v.w));
#pragma unroll
    for (int off = 32; off > 0; off >>= 1) m = fmaxf(m, __shfl_down(m, off));
    const int wid = t >> 6, lane = t & 63;
    if (lane == 0) sm[wid] = m;
    __syncthreads();
    m = fmaxf(fmaxf(sm[0], sm[1]), fmaxf(sm[2], sm[3]));

    v.x = __expf(v.x - m); v.y = __expf(v.y - m);
    v.z = __expf(v.z - m); v.w = __expf(v.w - m);
    float s = v.x + v.y + v.z + v.w;
#pragma unroll
    for (int off = 32; off > 0; off >>= 1) s += __shfl_down(s, off);
    if (lane == 0) ss[wid] = s;
    __syncthreads();
    s = ss[0] + ss[1] + ss[2] + ss[3];

    const float inv = 1.f / s;
    v.x *= inv; v.y *= inv; v.z *= inv; v.w *= inv;
    *(float4*)&p[t * 4] = v;
}

// ---------------------------------------------------------------------------
// out[bc,y,x] = osm[bc, (y/8)*32 + x/8] + x[bc,y,x].  Works for full tensor
// (grid covers B*C*H*W/4, bc = 0..2047) or one batch (grid C*H*W/4, bc=c).
// osm must NOT alias out (it lives in d_ws).
// ---------------------------------------------------------------------------
__global__ __launch_bounds__(256) void final_kernel(
    const float* __restrict__ x, const float* __restrict__ osm,
    float* __restrict__ out)
{
    size_t f   = (size_t)blockIdx.x * 256 + threadIdx.x;  // float4 index
    int    x4  = (int)(f & 63);          // W/4 = 64
    int    y   = (int)((f >> 6) & 255);
    size_t bc  = f >> 14;
    int    n   = ((y >> 3) << 5) + (x4 >> 1);
    float  s   = osm[(bc << 10) + n];
    float4 xv  = ((const float4*)x)[f];
    ((float4*)out)[f] = make_float4(xv.x + s, xv.y + s, xv.z + s, xv.w + s);
}

// ---------------------------------------------------------------------------
extern "C" void kernel_launch(void* const* d_in, const int* in_sizes, int n_in,
                              void* d_out, int out_size, void* d_ws, size_t ws_size,
                              hipStream_t stream)
{
    const float* x  = (const float*)d_in[0];
    const float* Wq = (const float*)d_in[1];
    const float* bq = (const float*)d_in[2];
    const float* Wk = (const float*)d_in[3];
    const float* bk = (const float*)d_in[4];
    const float* Wv = (const float*)d_in[5];
    const float* bv = (const float*)d_in[6];
    float* out = (float*)d_out;

    // ---- scratch lives in d_out's batch-3 quarter (dead before final writes) ----
    // d_out has B*C*H*W = 134,217,728 floats; batch-3 region starts at:
    float* scratch = out + (size_t)3 * C_ * H_ * W_;      // 33,554,432 floats avail
    float* xf   = scratch;                  // 2,097,152  [B*C, 1024]
    float* Y    = xf   + 2097152;           // 2,621,440  [B, 640, 1024]
    float* attn = Y    + 2621440;           // 4,194,304  [B, 1024, 1024]
    float* Wcat = attn + 4194304;           // 327,680
    float* bcat = Wcat + 327680;            // 640        (total 9,241,216 < 33.5M)

    // ---- only osm (read while out is being written) must live in d_ws ----
    const bool full_osm = ws_size >= (size_t)C_ * N_ * B_ * sizeof(float);  // 8 MB
    float* osm = (float*)d_ws;   // mode A: [B,C,1024]; mode B: [C,1024] slice

    // 1) concat weights/biases
    concat_kernel<<<dim3(1280), dim3(256), 0, stream>>>(Wq, bq, Wk, bk, Wv, bv, Wcat, bcat);

    // 2) avg-pool 8x8
    pool_kernel<<<dim3((B_ * C_ * N_) / 256), dim3(256), 0, stream>>>(x, xf);

    // 3) fused QKV: Y[b,j,n] = Wcat[j,:].xf[b,:,n] + bcat[j]
    gemm_kernel<true, true><<<dim3(8, 10, 4), dim3(256), 0, stream>>>(
        Wcat, 512, 1, 0,
        xf, 1024, 1, (long)C_ * N_,
        Y, 1024, (long)MR_ * N_,
        C_, bcat, 1.f);

    // 4) energy: attn[b,n,m] = 0.125 * sum_k qT[k,n]*kmat[k,m]
    gemm_kernel<false, true><<<dim3(8, 16, 4), dim3(256), 0, stream>>>(
        Y, 1, 1024, (long)MR_ * N_,
        Y + 64 * 1024, 1024, 1, (long)MR_ * N_,
        attn, 1024, (long)N_ * N_,
        KD_, nullptr, 0.125f);

    // 5) softmax over rows
    softmax_kernel<<<dim3(B_ * N_), dim3(256), 0, stream>>>(attn);

    if (full_osm) {
        // 6) PV: osm[b,d,m] = sum_n v[d,n]*attn[m,n]
        gemm_kernel<true, false><<<dim3(8, 8, 4), dim3(256), 0, stream>>>(
            Y + 128 * 1024, 1024, 1, (long)MR_ * N_,
            attn, 1, 1024, (long)N_ * N_,
            osm, 1024, (long)C_ * N_,
            N_, nullptr, 1.f);
        // 7) upsample + residual, whole tensor (clobbers scratch; osm is in ws)
        final_kernel<<<dim3((B_ * C_ * H_ * W_ / 4) / 256), dim3(256), 0, stream>>>(
            x, osm, out);
    } else {
        // Per-batch: 2 MB osm slice in ws; final_3 clobbers scratch only after
        // its last reader (PV_3) completed.
        for (int b = 0; b < B_; ++b) {
            gemm_kernel<true, false><<<dim3(8, 8, 1), dim3(256), 0, stream>>>(
                Y + 128 * 1024 + (size_t)b * MR_ * N_, 1024, 1, 0,
                attn + (size_t)b * N_ * N_, 1, 1024, 0,
                osm, 1024, 0,
                N_, nullptr, 1.f);
            final_kernel<<<dim3((C_ * H_ * W_ / 4) / 256), dim3(256), 0, stream>>>(
                x + (size_t)b * C_ * H_ * W_, osm, out + (size_t)b * C_ * H_ * W_);
        }
    }
}